// Round 7
// baseline (262.376 us; speedup 1.0000x reference)
//
#include <hip/hip_runtime.h>
#include <math.h>

#define EPS_YAT (1.0f/137.0f)

typedef unsigned short u16;
typedef unsigned int u32;
typedef __attribute__((ext_vector_type(8))) __bf16 bf16x8;
typedef __attribute__((ext_vector_type(4))) float f32x4;

__device__ __forceinline__ float4 ld4(const float* p) { return *(const float4*)p; }

__device__ __forceinline__ u16 bf16_rne(float f) {
    u32 u = __float_as_uint(f);
    u32 r = (u + 0x7fffu + ((u >> 16) & 1u)) >> 16;
    return (u16)r;
}
__device__ __forceinline__ float bf16_f(u16 h) {
    return __uint_as_float(((u32)h) << 16);
}

// async global->LDS DMA, 16B per lane. LDS dest is wave-uniform base + lane*16
// (m104); global src is per-lane (m173).
__device__ __forceinline__ void glds16(const u16* g, u16* s) {
    __builtin_amdgcn_global_load_lds(
        (const __attribute__((address_space(1))) void*)g,
        (__attribute__((address_space(3))) void*)s,
        16, 0, 0);
}

// ---- column-norm partials of W [K,N]: grid (N/64, 16), K-parallel ----
__global__ void colnorm_part(const float* __restrict__ W, float* __restrict__ part,
                             int K, int N) {
    __shared__ float sm[256];
    const int col = blockIdx.x * 64 + (threadIdx.x & 63);
    const int q = threadIdx.x >> 6;                    // 0..3
    const int rows = K >> 6;                           // 12 rows per thread
    const int k0 = blockIdx.y * (K >> 4) + q * rows;   // slice of 48 rows
    float s = 0.f;
    for (int k = k0; k < k0 + rows; ++k) {
        float w = W[(size_t)k * N + col];
        s += w * w;
    }
    sm[threadIdx.x] = s;
    __syncthreads();
    if (threadIdx.x < 64)
        part[(size_t)blockIdx.y * N + col] =
            sm[threadIdx.x] + sm[threadIdx.x + 64] + sm[threadIdx.x + 128] + sm[threadIdx.x + 192];
}

__global__ void colnorm_reduce(const float* __restrict__ part, float* __restrict__ wn,
                               int N) {
    int gid = blockIdx.x * 256 + threadIdx.x;
    if (gid >= N) return;
    float s = 0.f;
    #pragma unroll
    for (int i = 0; i < 16; ++i) s += part[(size_t)i * N + gid];
    wn[gid] = s;
}

// ---- fused bf16 double-split + row norms of x (K=768): one read pass ----
__global__ void split_rownorm(const float* __restrict__ X, u16* __restrict__ Xh,
                              u16* __restrict__ Xl, float* __restrict__ rn) {
    int wave = threadIdx.x >> 6;
    int lane = threadIdx.x & 63;
    int row = blockIdx.x * 4 + wave;
    const float* xr = X + (size_t)row * 768;
    u16* xh = Xh + (size_t)row * 768;
    u16* xl = Xl + (size_t)row * 768;
    float s = 0.f;
    #pragma unroll
    for (int k = lane * 4; k < 768; k += 256) {
        float4 v = ld4(xr + k);
        s += v.x * v.x + v.y * v.y + v.z * v.z + v.w * v.w;
        u16 h0 = bf16_rne(v.x), h1 = bf16_rne(v.y), h2 = bf16_rne(v.z), h3 = bf16_rne(v.w);
        u16 l0 = bf16_rne(v.x - bf16_f(h0));
        u16 l1 = bf16_rne(v.y - bf16_f(h1));
        u16 l2 = bf16_rne(v.z - bf16_f(h2));
        u16 l3 = bf16_rne(v.w - bf16_f(h3));
        uint2 hp, lp;
        hp.x = (u32)h0 | ((u32)h1 << 16); hp.y = (u32)h2 | ((u32)h3 << 16);
        lp.x = (u32)l0 | ((u32)l1 << 16); lp.y = (u32)l2 | ((u32)l3 << 16);
        *(uint2*)(xh + k) = hp;
        *(uint2*)(xl + k) = lp;
    }
    for (int off = 32; off; off >>= 1) s += __shfl_down(s, off);
    if (lane == 0) rn[row] = s;
}

// ---- row norms from h/l split input (K=768 fixed) ----
__global__ void rownorm_hl(const u16* __restrict__ Xh, const u16* __restrict__ Xl,
                           float* __restrict__ rn) {
    int wave = threadIdx.x >> 6;
    int lane = threadIdx.x & 63;
    int row = blockIdx.x * 4 + wave;
    const u16* xh = Xh + (size_t)row * 768;
    const u16* xl = Xl + (size_t)row * 768;
    float s = 0.f;
    for (int k = lane * 4; k < 768; k += 256) {
        uint2 hv = *(const uint2*)(xh + k);
        uint2 lv = *(const uint2*)(xl + k);
        float a0 = bf16_f((u16)hv.x)         + bf16_f((u16)lv.x);
        float a1 = bf16_f((u16)(hv.x >> 16)) + bf16_f((u16)(lv.x >> 16));
        float a2 = bf16_f((u16)hv.y)         + bf16_f((u16)lv.y);
        float a3 = bf16_f((u16)(hv.y >> 16)) + bf16_f((u16)(lv.y >> 16));
        s += a0 * a0 + a1 * a1 + a2 * a2 + a3 * a3;
    }
    for (int off = 32; off; off >>= 1) s += __shfl_down(s, off);
    if (lane == 0) rn[row] = s;
}

// ---- q/k norms from pre-split qkv (h+l reconstruction) ----
__global__ void qknorm_kernel(const u16* __restrict__ qh, const u16* __restrict__ ql,
                              float* __restrict__ qn, float* __restrict__ kn) {
    int gid = blockIdx.x * 256 + threadIdx.x;
    int lane = gid & 15;
    int idx = gid >> 4;
    int which = (idx >= 49152) ? 1 : 0;
    int r = idx - which * 49152;
    int t = r & 1023;
    int bh = r >> 10;
    int h = bh % 12, b = bh / 12;
    const size_t off = (size_t)(b * 1024 + t) * 2304 + which * 768 + h * 64 + lane * 4;
    uint2 hv = *(const uint2*)(qh + off);
    uint2 lv = *(const uint2*)(ql + off);
    float a0 = bf16_f((u16)hv.x)         + bf16_f((u16)lv.x);
    float a1 = bf16_f((u16)(hv.x >> 16)) + bf16_f((u16)(lv.x >> 16));
    float a2 = bf16_f((u16)hv.y)         + bf16_f((u16)lv.y);
    float a3 = bf16_f((u16)(hv.y >> 16)) + bf16_f((u16)(lv.y >> 16));
    float s = a0 * a0 + a1 * a1 + a2 * a2 + a3 * a3;
    s += __shfl_xor(s, 1, 16);
    s += __shfl_xor(s, 2, 16);
    s += __shfl_xor(s, 4, 16);
    s += __shfl_xor(s, 8, 16);
    if (lane == 0) (which ? kn : qn)[r] = s;
}

// ---- transpose + bf16 double-split: W [K][N] -> Th, Tl [N][K] ----
__global__ void split_wt_kernel(const float* __restrict__ W, u16* __restrict__ Th,
                                u16* __restrict__ Tl, int K, int N) {
    __shared__ float tile[64 * 68];
    const int tid = threadIdx.x;
    const int n0 = blockIdx.x << 6;
    const int k0 = blockIdx.y << 6;
    const int rr = tid >> 4;
    const int cc = (tid & 15) << 2;
    #pragma unroll
    for (int s = 0; s < 4; ++s) {
        int k_l = rr + s * 16;
        *(float4*)&tile[k_l * 68 + cc] = ld4(W + (size_t)(k0 + k_l) * N + n0 + cc);
    }
    __syncthreads();
    #pragma unroll
    for (int s = 0; s < 4; ++s) {
        int n_l = rr + s * 16;
        float a0 = tile[(cc + 0) * 68 + n_l];
        float a1 = tile[(cc + 1) * 68 + n_l];
        float a2 = tile[(cc + 2) * 68 + n_l];
        float a3 = tile[(cc + 3) * 68 + n_l];
        u16 h0 = bf16_rne(a0), h1 = bf16_rne(a1), h2 = bf16_rne(a2), h3 = bf16_rne(a3);
        u16 l0 = bf16_rne(a0 - bf16_f(h0));
        u16 l1 = bf16_rne(a1 - bf16_f(h1));
        u16 l2 = bf16_rne(a2 - bf16_f(h2));
        u16 l3 = bf16_rne(a3 - bf16_f(h3));
        uint2 hp, lp;
        hp.x = (u32)h0 | ((u32)h1 << 16); hp.y = (u32)h2 | ((u32)h3 << 16);
        lp.x = (u32)l0 | ((u32)l1 << 16); lp.y = (u32)l2 | ((u32)l3 << 16);
        size_t o = (size_t)(n0 + n_l) * K + k0 + cc;
        *(uint2*)(Th + o) = hp;
        *(uint2*)(Tl + o) = lp;
    }
}

// ---- yat GEMM: 64x(64*NB) tiles, single-buffer gload_lds, m97 2-barrier loop.
// R7: launch_bounds(256,6) -> 6 blocks/CU (24KB LDS x6 = 144 <= 160KB; 48 VGPR
// x 6 waves/SIMD = 288 <= 512). Grid 1152/768 both fully resident in ONE round
// (1536 slots): zero tail + 1.5x TLP to stagger the per-K-step DMA stalls
// (m97 mechanism: this structure converts latency to throughput via TLP only).
template<int SPLIT, int NB>   // NB: per-wave n-subtiles; tile = 64 x (64*NB)
__global__ __launch_bounds__(256, 6)
void yat_gemm_mfma(const u16* __restrict__ Ah, const u16* __restrict__ Al,
                   const u16* __restrict__ Bh, const u16* __restrict__ Bl,
                   const float* __restrict__ bias, const float* __restrict__ xn,
                   const float* __restrict__ wnc, const float* __restrict__ alphap,
                   const float Fdim, float* __restrict__ out,
                   u16* __restrict__ outh, u16* __restrict__ outl,
                   const int N, const int K) {
    __shared__ __align__(16) u16 lds[4096 + NB * 4096];
    const int tid = threadIdx.x;
    // XCD swizzle: nwg % 8 == 0 for both launches (1152, 768)
    const int nwg = gridDim.x * gridDim.y;
    const int orig = blockIdx.y * gridDim.x + blockIdx.x;
    const int swz = (orig & 7) * (nwg >> 3) + (orig >> 3);
    const int m0 = (swz / gridDim.x) << 6;
    const int n0 = (swz % gridDim.x) * (64 * NB);
    const int w = tid >> 6;
    const int l = tid & 63;
    const int lm = l & 15;
    const int kq = l >> 4;
    const int kq4 = kq << 2;
    const int wn = w * 16 * NB;

    const int srow = (w << 4) + (l >> 2);
    const int scol = (l & 3) << 3;
    const u16* gA  = Ah + (size_t)(m0 + srow) * K + scol;
    const u16* gC  = Al + (size_t)(m0 + srow) * K + scol;
    const u16* gB  = Bh + (size_t)(n0 + srow) * K + scol;
    const u16* gD  = Bl + (size_t)(n0 + srow) * K + scol;
    const u16* gB2 = Bh + (size_t)(n0 + 64 + srow) * K + scol;
    const u16* gD2 = Bl + (size_t)(n0 + 64 + srow) * K + scol;
    const int wb = w << 9;

    u16* sAh = lds;
    u16* sAl = lds + 2048;
    u16* sBh = lds + 4096;
    u16* sBl = lds + 4096 + 2048 * NB;

    f32x4 acc[4][NB] = {};

    for (int k0 = 0; k0 < K; k0 += 32) {
        __syncthreads();                    // prior tile's frag reads done
        glds16(gA + k0, sAh + wb);
        glds16(gC + k0, sAl + wb);
        glds16(gB + k0, sBh + wb);
        glds16(gD + k0, sBl + wb);
        if constexpr (NB == 2) {
            glds16(gB2 + k0, sBh + 2048 + wb);
            glds16(gD2 + k0, sBl + 2048 + wb);
        }
        __syncthreads();                    // implicit vmcnt(0): tile staged

        bf16x8 fah[4], fal[4], fbh[NB], fbl[NB];
        #pragma unroll
        for (int i = 0; i < 4; ++i) {
            const int ra = (i * 16 + lm) * 32 + (kq << 3);
            fah[i] = *(const bf16x8*)&sAh[ra];
            fal[i] = *(const bf16x8*)&sAl[ra];
        }
        #pragma unroll
        for (int j = 0; j < NB; ++j) {
            const int rb = (wn + j * 16 + lm) * 32 + (kq << 3);
            fbh[j] = *(const bf16x8*)&sBh[rb];
            fbl[j] = *(const bf16x8*)&sBl[rb];
        }
        #pragma unroll
        for (int i = 0; i < 4; ++i)
            #pragma unroll
            for (int j = 0; j < NB; ++j) {
                f32x4 c = acc[i][j];
                c = __builtin_amdgcn_mfma_f32_16x16x32_bf16(fah[i], fbh[j], c, 0, 0, 0);
                c = __builtin_amdgcn_mfma_f32_16x16x32_bf16(fah[i], fbl[j], c, 0, 0, 0);
                c = __builtin_amdgcn_mfma_f32_16x16x32_bf16(fal[i], fbh[j], c, 0, 0, 0);
                acc[i][j] = c;
            }
    }

    const float scale = powf(sqrtf(Fdim) / log1pf(Fdim), *alphap);
    #pragma unroll
    for (int i = 0; i < 4; ++i) {
        const int mbase = m0 + i * 16 + kq4;
        #pragma unroll
        for (int j = 0; j < NB; ++j) {
            const int n = n0 + wn + j * 16 + lm;
            const float w2 = wnc[n];
            const float bv = bias[n];
            #pragma unroll
            for (int r = 0; r < 4; ++r) {
                const int m = mbase + r;
                float d = acc[i][j][r];
                float den = xn[m] + w2 - 2.f * d + EPS_YAT;
                float v = (d * d / den + bv) * scale;
                if constexpr (SPLIT) {
                    u16 hh = bf16_rne(v);
                    outh[(size_t)m * N + n] = hh;
                    outl[(size_t)m * N + n] = bf16_rne(v - bf16_f(hh));
                } else {
                    out[(size_t)m * N + n] = v;
                }
            }
        }
    }
}

// ======================= MFMA flash attention (yat score) ====================
// launch_bounds(256,2): (256,4) capped VGPR at 64 and spilled (R5 lesson).
// 37.4KB LDS still gives 4 blocks/CU.
#define MFMA_B16(a, b, c) __builtin_amdgcn_mfma_f32_16x16x32_bf16(a, b, c, 0, 0, 0)

#define ST_TILE(j) { \
    const int kro = ((j)*16 + lm) * 72 + (kq << 3); \
    bf16x8 kh = *(const bf16x8*)&KPh[kro]; \
    bf16x8 kl = *(const bf16x8*)&KPl[kro]; \
    st##j = MFMA_B16(kh, qh0, st##j); \
    st##j = MFMA_B16(kl, qh0, st##j); \
    st##j = MFMA_B16(kh, ql0, st##j); \
    kh = *(const bf16x8*)&KPh[kro + 32]; \
    kl = *(const bf16x8*)&KPl[kro + 32]; \
    st##j = MFMA_B16(kh, qh1, st##j); \
    st##j = MFMA_B16(kl, qh1, st##j); \
    st##j = MFMA_B16(kh, ql1, st##j); \
}

#define YAT_EL(j, r) { \
    float sv = st##j[r] * 0.125f; \
    float den = qnm + kns[(j)*16 + kq4 + (r)] - 2.f * sv + EPS_YAT; \
    float v = sv * sv / den; \
    if (diag && ((j)*16 + kq4 + (r) > wband + lm)) v = -3e38f; \
    st##j[r] = v; mm = fmaxf(mm, v); }
#define YAT_TILE(j) YAT_EL(j,0) YAT_EL(j,1) YAT_EL(j,2) YAT_EL(j,3)

#define PEXP_TILE(j) { \
    float p0 = __expf(st##j[0] - mnew), p1 = __expf(st##j[1] - mnew); \
    float p2 = __expf(st##j[2] - mnew), p3 = __expf(st##j[3] - mnew); \
    rs += p0 + p1 + p2 + p3; \
    u16 h0 = bf16_rne(p0), h1 = bf16_rne(p1), h2 = bf16_rne(p2), h3 = bf16_rne(p3); \
    uint2 hp; hp.x = (u32)h0 | ((u32)h1 << 16); hp.y = (u32)h2 | ((u32)h3 << 16); \
    *(uint2*)&KPh[pmrow + (j)*16 + kq4] = hp; \
    u16 e0 = bf16_rne(p0 - bf16_f(h0)), e1 = bf16_rne(p1 - bf16_f(h1)); \
    u16 e2 = bf16_rne(p2 - bf16_f(h2)), e3 = bf16_rne(p3 - bf16_f(h3)); \
    uint2 lp; lp.x = (u32)e0 | ((u32)e1 << 16); lp.y = (u32)e2 | ((u32)e3 << 16); \
    *(uint2*)&KPl[pmrow + (j)*16 + kq4] = lp; }

#define PV_TILE(j) { \
    const int vro = ((j)*16 + lm) * 72 + vkq8; \
    bf16x8 vh = *(const bf16x8*)&Vth[vro]; \
    bf16x8 vl = *(const bf16x8*)&Vtl[vro]; \
    ac##j = MFMA_B16(ph0, vh, ac##j); \
    ac##j = MFMA_B16(pl0, vh, ac##j); \
    ac##j = MFMA_B16(ph0, vl, ac##j); \
    vh = *(const bf16x8*)&Vth[vro + 32]; \
    vl = *(const bf16x8*)&Vtl[vro + 32]; \
    ac##j = MFMA_B16(ph1, vh, ac##j); \
    ac##j = MFMA_B16(pl1, vh, ac##j); \
    ac##j = MFMA_B16(ph1, vl, ac##j); \
}

// transposed V staging from a pre-split uint2 (4 u16 along d), token column toks
#define WRVT(dst, v2, m) { \
    dst[(sj * 4 + 16 * (m) + 0) * 72 + toks] = (u16)((v2).x); \
    dst[(sj * 4 + 16 * (m) + 1) * 72 + toks] = (u16)((v2).x >> 16); \
    dst[(sj * 4 + 16 * (m) + 2) * 72 + toks] = (u16)((v2).y); \
    dst[(sj * 4 + 16 * (m) + 3) * 72 + toks] = (u16)((v2).y >> 16); }

__global__ __launch_bounds__(256, 2)
void yat_flash_mfma(const u16* __restrict__ qh_g, const u16* __restrict__ ql_g,
                    const float* __restrict__ qn, const float* __restrict__ kn,
                    u16* __restrict__ outh, u16* __restrict__ outl) {
    __shared__ __align__(16) u16 KPh[64 * 72], KPl[64 * 72];  // Q prologue; K; P after St
    __shared__ __align__(16) u16 Vth[64 * 72], Vtl[64 * 72];  // V^T [d][tok^swz]
    __shared__ float kns[64];

    const int tid = threadIdx.x;
    const int L = blockIdx.x;         // 0..767
    const int u = L / 48;
    const int qt = (u & 1) ? (u >> 1) : (15 - (u >> 1));
    const int bh = L % 48;
    const int h = bh % 12, b = bh / 12;
    const int wave = tid >> 6;
    const int lane = tid & 63;
    const int lm = lane & 15;
    const int kq = lane >> 4;
    const int kq4 = kq << 2;
    const int wband = wave << 4;
    const int sr = tid >> 2;          // staging token row 0..63
    const int sj = tid & 3;           // staging d-group
    const int toks = sr ^ (sj << 3);  // swizzled Vt column
    const int vkq8 = (kq ^ (lm >> 2)) << 3;
    const size_t base = (size_t)(b * 1024) * 2304 + h * 64;

    // ---- stage Q through KPh/KPl (only needed until frag reads) ----
    {
        const size_t qoff = base + (size_t)((qt << 6) + sr) * 2304 + sj * 16;
        *(uint4*)&KPh[sr * 72 + sj * 16]     = *(const uint4*)(qh_g + qoff);
        *(uint4*)&KPh[sr * 72 + sj * 16 + 8] = *(const uint4*)(qh_g + qoff + 8);
        *(uint4*)&KPl[sr * 72 + sj * 16]     = *(const uint4*)(ql_g + qoff);
        *(uint4*)&KPl[sr * 72 + sj * 16 + 8] = *(const uint4*)(ql_g + qoff + 8);
    }
    const float qnm = qn[bh * 1024 + (qt << 6) + wband + lm];

    // prefetch kt=0 K/V (pre-split u16) into registers
    const size_t r0 = base + (size_t)sr * 2304;
    uint4 kh0 = *(const uint4*)(qh_g + r0 + 768 + sj * 16);
    uint4 kh1 = *(const uint4*)(qh_g + r0 + 768 + sj * 16 + 8);
    uint4 kl0 = *(const uint4*)(ql_g + r0 + 768 + sj * 16);
    uint4 kl1 = *(const uint4*)(ql_g + r0 + 768 + sj * 16 + 8);
    uint2 vh0 = *(const uint2*)(qh_g + r0 + 1536 + sj * 4);
    uint2 vh1 = *(const uint2*)(qh_g + r0 + 1536 + sj * 4 + 16);
    uint2 vh2 = *(const uint2*)(qh_g + r0 + 1536 + sj * 4 + 32);
    uint2 vh3 = *(const uint2*)(qh_g + r0 + 1536 + sj * 4 + 48);
    uint2 vl0 = *(const uint2*)(ql_g + r0 + 1536 + sj * 4);
    uint2 vl1 = *(const uint2*)(ql_g + r0 + 1536 + sj * 4 + 16);
    uint2 vl2 = *(const uint2*)(ql_g + r0 + 1536 + sj * 4 + 32);
    uint2 vl3 = *(const uint2*)(ql_g + r0 + 1536 + sj * 4 + 48);
    float knS = (tid < 64) ? kn[bh * 1024 + tid] : 0.f;

    __syncthreads();  // Q staged

    // loop-invariant Q fragments (B-operand: Q^T via row-major Q)
    const int qrow = (wband + lm) * 72;
    const bf16x8 qh0 = *(const bf16x8*)&KPh[qrow + (kq << 3)];
    const bf16x8 qh1 = *(const bf16x8*)&KPh[qrow + 32 + (kq << 3)];
    const bf16x8 ql0 = *(const bf16x8*)&KPl[qrow + (kq << 3)];
    const bf16x8 ql1 = *(const bf16x8*)&KPl[qrow + 32 + (kq << 3)];

    f32x4 ac0 = {}, ac1 = {}, ac2 = {}, ac3 = {};
    float mrun = -3e38f, lrun = 0.f;
    const int pmrow = (wband + lm) * 72;

    for (int kt = 0; kt <= qt; ++kt) {
        __syncthreads();  // Q frag reads (iter0) / prior PV reads done
        *(uint4*)&KPh[sr * 72 + sj * 16]     = kh0;
        *(uint4*)&KPh[sr * 72 + sj * 16 + 8] = kh1;
        *(uint4*)&KPl[sr * 72 + sj * 16]     = kl0;
        *(uint4*)&KPl[sr * 72 + sj * 16 + 8] = kl1;
        WRVT(Vth, vh0, 0) WRVT(Vth, vh1, 1) WRVT(Vth, vh2, 2) WRVT(Vth, vh3, 3)
        WRVT(Vtl, vl0, 0) WRVT(Vtl, vl1, 1) WRVT(Vtl, vl2, 2) WRVT(Vtl, vl3, 3)
        if (tid < 64) kns[tid] = knS;
        __syncthreads();

        if (kt < qt) {  // prefetch kt+1 (block-uniform)
            const size_t r = base + (size_t)(((kt + 1) << 6) + sr) * 2304;
            kh0 = *(const uint4*)(qh_g + r + 768 + sj * 16);
            kh1 = *(const uint4*)(qh_g + r + 768 + sj * 16 + 8);
            kl0 = *(const uint4*)(ql_g + r + 768 + sj * 16);
            kl1 = *(const uint4*)(ql_g + r + 768 + sj * 16 + 8);
            vh0 = *(const uint2*)(qh_g + r + 1536 + sj * 4);
            vh1 = *(const uint2*)(qh_g + r + 1536 + sj * 4 + 16);
            vh2 = *(const uint2*)(qh_g + r + 1536 + sj * 4 + 32);
            vh3 = *(const uint2*)(qh_g + r + 1536 + sj * 4 + 48);
            vl0 = *(const uint2*)(ql_g + r + 1536 + sj * 4);
            vl1 = *(const uint2*)(ql_g + r + 1536 + sj * 4 + 16);
            vl2 = *(const uint2*)(ql_g + r + 1536 + sj * 4 + 32);
            vl3 = *(const uint2*)(ql_g + r + 1536 + sj * 4 + 48);
            if (tid < 64) knS = kn[bh * 1024 + ((kt + 1) << 6) + tid];
        }

        // ---- St = K.Q^T (each lane: one m = wband+lm, n = j*16+kq*4+r) ----
        f32x4 st0 = {}, st1 = {}, st2 = {}, st3 = {};
        __builtin_amdgcn_s_setprio(1);
        ST_TILE(0) ST_TILE(1) ST_TILE(2) ST_TILE(3)
        __builtin_amdgcn_s_setprio(0);
        __syncthreads();  // K frag reads done; P may overwrite KP

        // ---- yat score + mask + online softmax (per-lane row state) ----
        const bool diag = (kt == qt);
        float mm = -3e38f;
        YAT_TILE(0) YAT_TILE(1) YAT_TILE(2) YAT_TILE(3)
        mm = fmaxf(mm, __shfl_xor(mm, 16));
        mm = fmaxf(mm, __shfl_xor(mm, 32));
        const float mnew = fmaxf(mrun, mm);
        const float al = __expf(mrun - mnew);
        mrun = mnew;
        float rs = 0.f;
        PEXP_TILE(0) PEXP_TILE(1) PEXP_TILE(2) PEXP_TILE(3)
        rs += __shfl_xor(rs, 16);
        rs += __shfl_xor(rs, 32);
        lrun = lrun * al + rs;
        const float a0 = __shfl(al, kq4 + 0, 16);
        const float a1 = __shfl(al, kq4 + 1, 16);
        const float a2 = __shfl(al, kq4 + 2, 16);
        const float a3 = __shfl(al, kq4 + 3, 16);
        ac0[0] *= a0; ac0[1] *= a1; ac0[2] *= a2; ac0[3] *= a3;
        ac1[0] *= a0; ac1[1] *= a1; ac1[2] *= a2; ac1[3] *= a3;
        ac2[0] *= a0; ac2[1] *= a1; ac2[2] *= a2; ac2[3] *= a3;
        ac3[0] *= a0; ac3[1] *= a1; ac3[2] *= a2; ac3[3] *= a3;
        __syncthreads();  // P writes visible

        // ---- O += P.V ----
        const bf16x8 ph0 = *(const bf16x8*)&KPh[pmrow + (kq << 3)];
        const bf16x8 ph1 = *(const bf16x8*)&KPh[pmrow + 32 + (kq << 3)];
        const bf16x8 pl0 = *(const bf16x8*)&KPl[pmrow + (kq << 3)];
        const bf16x8 pl1 = *(const bf16x8*)&KPl[pmrow + 32 + (kq << 3)];
        __builtin_amdgcn_s_setprio(1);
        PV_TILE(0) PV_TILE(1) PV_TILE(2) PV_TILE(3)
        __builtin_amdgcn_s_setprio(0);
    }

    const float i0 = 1.f / __shfl(lrun, kq4 + 0, 16);
    const float i1 = 1.f / __shfl(lrun, kq4 + 1, 16);
    const float i2 = 1.f / __shfl(lrun, kq4 + 2, 16);
    const float i3 = 1.f / __shfl(lrun, kq4 + 3, 16);
    const size_t obase = (size_t)(b * 1024 + (qt << 6) + wband + kq4) * 768 + h * 64 + lm;
    u16* oph = outh + obase;
    u16* opl = outl + obase;
    #define STORE_E(j, r, iv) { \
        float ov = ac##j[r] * iv; \
        u16 hh = bf16_rne(ov); \
        oph[(size_t)(r) * 768 + (j)*16] = hh; \
        opl[(size_t)(r) * 768 + (j)*16] = bf16_rne(ov - bf16_f(hh)); }
    #define STORE_T(j) { STORE_E(j,0,i0) STORE_E(j,1,i1) STORE_E(j,2,i2) STORE_E(j,3,i3) }
    STORE_T(0) STORE_T(1) STORE_T(2) STORE_T(3)
    #undef STORE_T
    #undef STORE_E
}

extern "C" void kernel_launch(void* const* d_in, const int* in_sizes, int n_in,
                              void* d_out, int out_size, void* d_ws, size_t ws_size,
                              hipStream_t stream) {
    const float* x          = (const float*)d_in[0];
    // d_in[1] = mask (causal, known structure — unused)
    const float* W_attn     = (const float*)d_in[2];
    const float* b_attn     = (const float*)d_in[3];
    const float* alpha_attn = (const float*)d_in[4];
    const float* W_proj     = (const float*)d_in[5];
    const float* b_proj     = (const float*)d_in[6];
    const float* alpha_proj = (const float*)d_in[7];

    float* ws       = (float*)d_ws;
    u16*   qkvh     = (u16*)ws;              // [0, 4718592) f32-slots
    u16*   qkvl     = (u16*)(ws + 4718592);  // [4718592, 9437184)
    float* xn       = ws + 12582912;         // 4096
    float* an       = ws + 12587008;         // 4096
    float* wn_attn  = ws + 12591104;         // 2304
    float* wn_proj  = ws + 12593408;         // 768
    float* qn       = ws + 12594176;         // 49152
    float* kn       = ws + 12643328;         // 49152

    // [9437184, 12582912) region timeline (serial stream):
    //   colnorm partials -> xh/xl (gemm1 inputs) -> aoh/aol (flash output)
    float* cn_part_a = ws + 9437184;              // 16*2304
    float* cn_part_p = ws + 9437184 + 36864;      // 16*768
    u16* xh  = (u16*)(ws + 9437184);
    u16* xl  = (u16*)(ws + 11010048);
    u16* aoh = (u16*)(ws + 9437184);              // flash h/l output (xh/xl dead)
    u16* aol = (u16*)(ws + 11010048);
    u16* wth = (u16*)d_out;
    u16* wtl = (u16*)d_out + 1769472;
    u16* wph = (u16*)(ws + 3145728);              // inside qkvh region (dead post-flash)
    u16* wpl = (u16*)(ws + 3440640);

    colnorm_part<<<dim3(36, 16), 256, 0, stream>>>(W_attn, cn_part_a, 768, 2304);
    colnorm_part<<<dim3(12, 16), 256, 0, stream>>>(W_proj, cn_part_p, 768, 768);
    colnorm_reduce<<<9, 256, 0, stream>>>(cn_part_a, wn_attn, 2304);
    colnorm_reduce<<<3, 256, 0, stream>>>(cn_part_p, wn_proj, 768);
    split_rownorm<<<1024, 256, 0, stream>>>(x, xh, xl, xn);
    split_wt_kernel<<<dim3(36, 12), 256, 0, stream>>>(W_attn, wth, wtl, 768, 2304);
    yat_gemm_mfma<1, 2><<<dim3(18, 64), 256, 0, stream>>>(
        xh, xl, wth, wtl, b_attn, xn, wn_attn, alpha_attn, 2304.f,
        nullptr, qkvh, qkvl, 2304, 768);
    qknorm_kernel<<<6144, 256, 0, stream>>>(qkvh, qkvl, qn, kn);
    yat_flash_mfma<<<768, 256, 0, stream>>>(qkvh, qkvl, qn, kn, aoh, aol);
    rownorm_hl<<<1024, 256, 0, stream>>>(aoh, aol, an);
    split_wt_kernel<<<dim3(12, 12), 256, 0, stream>>>(W_proj, wph, wpl, 768, 768);
    yat_gemm_mfma<0, 1><<<dim3(12, 64), 256, 0, stream>>>(
        aoh, aol, wph, wpl, b_proj, an, wn_proj, alpha_proj, 768.f,
        (float*)d_out, nullptr, nullptr, 768, 768);
}

// Round 8
// 248.006 us; speedup vs baseline: 1.0579x; 1.0579x over previous
//
#include <hip/hip_runtime.h>
#include <math.h>

#define EPS_YAT (1.0f/137.0f)

typedef unsigned short u16;
typedef unsigned int u32;
typedef __attribute__((ext_vector_type(8))) __bf16 bf16x8;
typedef __attribute__((ext_vector_type(4))) float f32x4;

__device__ __forceinline__ float4 ld4(const float* p) { return *(const float4*)p; }

__device__ __forceinline__ u16 bf16_rne(float f) {
    u32 u = __float_as_uint(f);
    u32 r = (u + 0x7fffu + ((u >> 16) & 1u)) >> 16;
    return (u16)r;
}
__device__ __forceinline__ float bf16_f(u16 h) {
    return __uint_as_float(((u32)h) << 16);
}

// async global->LDS DMA, 16B per lane. LDS dest is wave-uniform base + lane*16
// (m104); global src is per-lane (m173).
__device__ __forceinline__ void glds16(const u16* g, u16* s) {
    __builtin_amdgcn_global_load_lds(
        (const __attribute__((address_space(1))) void*)g,
        (__attribute__((address_space(3))) void*)s,
        16, 0, 0);
}

// ---- merged column-norm partials for BOTH weight matrices (K=768) ----
// grid (36+12, 16): x<36 -> W_attn cols, else W_proj cols.
__global__ void colnorm_part2(const float* __restrict__ Wa, const float* __restrict__ Wp,
                              float* __restrict__ pa, float* __restrict__ pp) {
    __shared__ float sm[256];
    const float* W; float* part; int N, colbase;
    if (blockIdx.x < 36) { W = Wa; part = pa; N = 2304; colbase = blockIdx.x * 64; }
    else                 { W = Wp; part = pp; N = 768;  colbase = (blockIdx.x - 36) * 64; }
    const int col = colbase + (threadIdx.x & 63);
    const int q = threadIdx.x >> 6;                 // 0..3
    const int k0 = blockIdx.y * 48 + q * 12;        // K=768: 16 slices x 48, 12/thread
    float s = 0.f;
    for (int k = k0; k < k0 + 12; ++k) {
        float w = W[(size_t)k * N + col];
        s += w * w;
    }
    sm[threadIdx.x] = s;
    __syncthreads();
    if (threadIdx.x < 64)
        part[(size_t)blockIdx.y * N + col] =
            sm[threadIdx.x] + sm[threadIdx.x + 64] + sm[threadIdx.x + 128] + sm[threadIdx.x + 192];
}

// merged reduce for both matrices + zero the an accumulator (flash atomics)
__global__ void colnorm_reduce2(const float* __restrict__ pa, const float* __restrict__ pp,
                                float* __restrict__ wa, float* __restrict__ wp,
                                float* __restrict__ an_zero) {
    int gid = blockIdx.x * 256 + threadIdx.x;
    if (gid < 2304) {
        float s = 0.f;
        #pragma unroll
        for (int i = 0; i < 16; ++i) s += pa[(size_t)i * 2304 + gid];
        wa[gid] = s;
    } else if (gid < 3072) {
        int g = gid - 2304;
        float s = 0.f;
        #pragma unroll
        for (int i = 0; i < 16; ++i) s += pp[(size_t)i * 768 + g];
        wp[g] = s;
    }
    int z = gid - 3072;
    if (z >= 0 && z < 4096) an_zero[z] = 0.f;
}

// ---- fused bf16 double-split + row norms of x (K=768): one read pass ----
__global__ void split_rownorm(const float* __restrict__ X, u16* __restrict__ Xh,
                              u16* __restrict__ Xl, float* __restrict__ rn) {
    int wave = threadIdx.x >> 6;
    int lane = threadIdx.x & 63;
    int row = blockIdx.x * 4 + wave;
    const float* xr = X + (size_t)row * 768;
    u16* xh = Xh + (size_t)row * 768;
    u16* xl = Xl + (size_t)row * 768;
    float s = 0.f;
    #pragma unroll
    for (int k = lane * 4; k < 768; k += 256) {
        float4 v = ld4(xr + k);
        s += v.x * v.x + v.y * v.y + v.z * v.z + v.w * v.w;
        u16 h0 = bf16_rne(v.x), h1 = bf16_rne(v.y), h2 = bf16_rne(v.z), h3 = bf16_rne(v.w);
        u16 l0 = bf16_rne(v.x - bf16_f(h0));
        u16 l1 = bf16_rne(v.y - bf16_f(h1));
        u16 l2 = bf16_rne(v.z - bf16_f(h2));
        u16 l3 = bf16_rne(v.w - bf16_f(h3));
        uint2 hp, lp;
        hp.x = (u32)h0 | ((u32)h1 << 16); hp.y = (u32)h2 | ((u32)h3 << 16);
        lp.x = (u32)l0 | ((u32)l1 << 16); lp.y = (u32)l2 | ((u32)l3 << 16);
        *(uint2*)(xh + k) = hp;
        *(uint2*)(xl + k) = lp;
    }
    for (int off = 32; off; off >>= 1) s += __shfl_down(s, off);
    if (lane == 0) rn[row] = s;
}

// ---- transpose + bf16 double-split: W [K][N] -> Th, Tl [N][K] ----
__global__ void split_wt_kernel(const float* __restrict__ W, u16* __restrict__ Th,
                                u16* __restrict__ Tl, int K, int N) {
    __shared__ float tile[64 * 68];
    const int tid = threadIdx.x;
    const int n0 = blockIdx.x << 6;
    const int k0 = blockIdx.y << 6;
    const int rr = tid >> 4;
    const int cc = (tid & 15) << 2;
    #pragma unroll
    for (int s = 0; s < 4; ++s) {
        int k_l = rr + s * 16;
        *(float4*)&tile[k_l * 68 + cc] = ld4(W + (size_t)(k0 + k_l) * N + n0 + cc);
    }
    __syncthreads();
    #pragma unroll
    for (int s = 0; s < 4; ++s) {
        int n_l = rr + s * 16;
        float a0 = tile[(cc + 0) * 68 + n_l];
        float a1 = tile[(cc + 1) * 68 + n_l];
        float a2 = tile[(cc + 2) * 68 + n_l];
        float a3 = tile[(cc + 3) * 68 + n_l];
        u16 h0 = bf16_rne(a0), h1 = bf16_rne(a1), h2 = bf16_rne(a2), h3 = bf16_rne(a3);
        u16 l0 = bf16_rne(a0 - bf16_f(h0));
        u16 l1 = bf16_rne(a1 - bf16_f(h1));
        u16 l2 = bf16_rne(a2 - bf16_f(h2));
        u16 l3 = bf16_rne(a3 - bf16_f(h3));
        uint2 hp, lp;
        hp.x = (u32)h0 | ((u32)h1 << 16); hp.y = (u32)h2 | ((u32)h3 << 16);
        lp.x = (u32)l0 | ((u32)l1 << 16); lp.y = (u32)l2 | ((u32)l3 << 16);
        size_t o = (size_t)(n0 + n_l) * K + k0 + cc;
        *(uint2*)(Th + o) = hp;
        *(uint2*)(Tl + o) = lp;
    }
}

// ---- yat GEMM: 64x(64*NB) tiles, single-buffer gload_lds, m97 2-barrier loop.
// (256,4): best measured config (R6 74.7 vs R7's (256,6) 77.9 — occupancy is
// NOT the limiter; structure ceiling for this short-K shape). SPLIT=1 also
// computes qn/kn IN the epilogue: each head's 64 cols lie entirely inside this
// block's 128-col range -> block-local reduction, direct store, no atomics.
// Removes the qknorm kernel (25MB re-read + launch).
template<int SPLIT, int NB>   // NB: per-wave n-subtiles; tile = 64 x (64*NB)
__global__ __launch_bounds__(256, 4)
void yat_gemm_mfma(const u16* __restrict__ Ah, const u16* __restrict__ Al,
                   const u16* __restrict__ Bh, const u16* __restrict__ Bl,
                   const float* __restrict__ bias, const float* __restrict__ xn,
                   const float* __restrict__ wnc, const float* __restrict__ alphap,
                   const float Fdim, float* __restrict__ out,
                   u16* __restrict__ outh, u16* __restrict__ outl,
                   float* __restrict__ qn, float* __restrict__ kn,
                   const int N, const int K) {
    __shared__ __align__(16) u16 lds[4096 + NB * 4096];
    const int tid = threadIdx.x;
    // XCD swizzle: nwg % 8 == 0 for both launches (1152, 768)
    const int nwg = gridDim.x * gridDim.y;
    const int orig = blockIdx.y * gridDim.x + blockIdx.x;
    const int swz = (orig & 7) * (nwg >> 3) + (orig >> 3);
    const int m0 = (swz / gridDim.x) << 6;
    const int n0 = (swz % gridDim.x) * (64 * NB);
    const int w = tid >> 6;
    const int l = tid & 63;
    const int lm = l & 15;
    const int kq = l >> 4;
    const int kq4 = kq << 2;
    const int wn = w * 16 * NB;

    const int srow = (w << 4) + (l >> 2);
    const int scol = (l & 3) << 3;
    const u16* gA  = Ah + (size_t)(m0 + srow) * K + scol;
    const u16* gC  = Al + (size_t)(m0 + srow) * K + scol;
    const u16* gB  = Bh + (size_t)(n0 + srow) * K + scol;
    const u16* gD  = Bl + (size_t)(n0 + srow) * K + scol;
    const u16* gB2 = Bh + (size_t)(n0 + 64 + srow) * K + scol;
    const u16* gD2 = Bl + (size_t)(n0 + 64 + srow) * K + scol;
    const int wb = w << 9;

    u16* sAh = lds;
    u16* sAl = lds + 2048;
    u16* sBh = lds + 4096;
    u16* sBl = lds + 4096 + 2048 * NB;

    f32x4 acc[4][NB] = {};

    for (int k0 = 0; k0 < K; k0 += 32) {
        __syncthreads();                    // prior tile's frag reads done
        glds16(gA + k0, sAh + wb);
        glds16(gC + k0, sAl + wb);
        glds16(gB + k0, sBh + wb);
        glds16(gD + k0, sBl + wb);
        if constexpr (NB == 2) {
            glds16(gB2 + k0, sBh + 2048 + wb);
            glds16(gD2 + k0, sBl + 2048 + wb);
        }
        __syncthreads();                    // implicit vmcnt(0): tile staged

        bf16x8 fah[4], fal[4], fbh[NB], fbl[NB];
        #pragma unroll
        for (int i = 0; i < 4; ++i) {
            const int ra = (i * 16 + lm) * 32 + (kq << 3);
            fah[i] = *(const bf16x8*)&sAh[ra];
            fal[i] = *(const bf16x8*)&sAl[ra];
        }
        #pragma unroll
        for (int j = 0; j < NB; ++j) {
            const int rb = (wn + j * 16 + lm) * 32 + (kq << 3);
            fbh[j] = *(const bf16x8*)&sBh[rb];
            fbl[j] = *(const bf16x8*)&sBl[rb];
        }
        #pragma unroll
        for (int i = 0; i < 4; ++i)
            #pragma unroll
            for (int j = 0; j < NB; ++j) {
                f32x4 c = acc[i][j];
                c = __builtin_amdgcn_mfma_f32_16x16x32_bf16(fah[i], fbh[j], c, 0, 0, 0);
                c = __builtin_amdgcn_mfma_f32_16x16x32_bf16(fah[i], fbl[j], c, 0, 0, 0);
                c = __builtin_amdgcn_mfma_f32_16x16x32_bf16(fal[i], fbh[j], c, 0, 0, 0);
                acc[i][j] = c;
            }
    }

    const float scale = powf(sqrtf(Fdim) / log1pf(Fdim), *alphap);
    float pp[4][4];   // per (i,r): sum of v^2 over this thread's NB cols
    #pragma unroll
    for (int i = 0; i < 4; ++i) {
        const int mbase = m0 + i * 16 + kq4;
        #pragma unroll
        for (int r = 0; r < 4; ++r) pp[i][r] = 0.f;
        #pragma unroll
        for (int j = 0; j < NB; ++j) {
            const int n = n0 + wn + j * 16 + lm;
            const float w2 = wnc[n];
            const float bv = bias[n];
            #pragma unroll
            for (int r = 0; r < 4; ++r) {
                const int m = mbase + r;
                float d = acc[i][j][r];
                float den = xn[m] + w2 - 2.f * d + EPS_YAT;
                float v = (d * d / den + bv) * scale;
                if constexpr (SPLIT) {
                    u16 hh = bf16_rne(v);
                    outh[(size_t)m * N + n] = hh;
                    outl[(size_t)m * N + n] = bf16_rne(v - bf16_f(hh));
                    pp[i][r] += v * v;
                } else {
                    out[(size_t)m * N + n] = v;
                }
            }
        }
    }

    if constexpr (SPLIT) {
        // fused q/k norms. Heads (64 cols) align to this block's n-range:
        // wave 0,1 cover head-half 0 (cols n0..n0+63), waves 2,3 half 1.
        if (n0 < 1536) {
            __syncthreads();  // k-loop LDS reads done; reuse lds as f32 scratch
            float* red = (float*)lds;   // [w][i*16+kq*4+r] = 4 x 64
            #pragma unroll
            for (int i = 0; i < 4; ++i)
                #pragma unroll
                for (int r = 0; r < 4; ++r) {
                    float s = pp[i][r];
                    s += __shfl_xor(s, 1, 16);
                    s += __shfl_xor(s, 2, 16);
                    s += __shfl_xor(s, 4, 16);
                    s += __shfl_xor(s, 8, 16);
                    if (lm == 0) red[w * 64 + i * 16 + kq4 + r] = s;
                }
            __syncthreads();
            if (tid < 128) {
                const int hh = tid >> 6;       // head half 0/1
                const int ml = tid & 63;       // i*16+kq*4+r == m - m0
                const float s = red[(2 * hh) * 64 + ml] + red[(2 * hh + 1) * 64 + ml];
                const int m = m0 + ml;
                const int b = m >> 10, t = m & 1023;
                const int hcol = n0 + hh * 64;
                if (hcol < 768)
                    qn[(b * 12 + (hcol >> 6)) * 1024 + t] = s;
                else
                    kn[(b * 12 + ((hcol - 768) >> 6)) * 1024 + t] = s;
            }
        }
    }
}

// ======================= MFMA flash attention (yat score) ====================
// (256,2): (256,4) capped VGPR at 64 and spilled (R5 lesson). R8: T13
// defer-max (skip O-rescale when no lane's max grew) + fused an row-norm
// (atomicAdd per wave-row; order jitter ~1e-7 of den — removes rownorm_hl).
#define MFMA_B16(a, b, c) __builtin_amdgcn_mfma_f32_16x16x32_bf16(a, b, c, 0, 0, 0)

#define ST_TILE(j) { \
    const int kro = ((j)*16 + lm) * 72 + (kq << 3); \
    bf16x8 kh = *(const bf16x8*)&KPh[kro]; \
    bf16x8 kl = *(const bf16x8*)&KPl[kro]; \
    st##j = MFMA_B16(kh, qh0, st##j); \
    st##j = MFMA_B16(kl, qh0, st##j); \
    st##j = MFMA_B16(kh, ql0, st##j); \
    kh = *(const bf16x8*)&KPh[kro + 32]; \
    kl = *(const bf16x8*)&KPl[kro + 32]; \
    st##j = MFMA_B16(kh, qh1, st##j); \
    st##j = MFMA_B16(kl, qh1, st##j); \
    st##j = MFMA_B16(kh, ql1, st##j); \
}

#define YAT_EL(j, r) { \
    float sv = st##j[r] * 0.125f; \
    float den = qnm + kns[(j)*16 + kq4 + (r)] - 2.f * sv + EPS_YAT; \
    float v = sv * sv / den; \
    if (diag && ((j)*16 + kq4 + (r) > wband + lm)) v = -3e38f; \
    st##j[r] = v; mm = fmaxf(mm, v); }
#define YAT_TILE(j) YAT_EL(j,0) YAT_EL(j,1) YAT_EL(j,2) YAT_EL(j,3)

#define PEXP_TILE(j) { \
    float p0 = __expf(st##j[0] - mnew), p1 = __expf(st##j[1] - mnew); \
    float p2 = __expf(st##j[2] - mnew), p3 = __expf(st##j[3] - mnew); \
    rs += p0 + p1 + p2 + p3; \
    u16 h0 = bf16_rne(p0), h1 = bf16_rne(p1), h2 = bf16_rne(p2), h3 = bf16_rne(p3); \
    uint2 hp; hp.x = (u32)h0 | ((u32)h1 << 16); hp.y = (u32)h2 | ((u32)h3 << 16); \
    *(uint2*)&KPh[pmrow + (j)*16 + kq4] = hp; \
    u16 e0 = bf16_rne(p0 - bf16_f(h0)), e1 = bf16_rne(p1 - bf16_f(h1)); \
    u16 e2 = bf16_rne(p2 - bf16_f(h2)), e3 = bf16_rne(p3 - bf16_f(h3)); \
    uint2 lp; lp.x = (u32)e0 | ((u32)e1 << 16); lp.y = (u32)e2 | ((u32)e3 << 16); \
    *(uint2*)&KPl[pmrow + (j)*16 + kq4] = lp; }

#define PV_TILE(j) { \
    const int vro = ((j)*16 + lm) * 72 + vkq8; \
    bf16x8 vh = *(const bf16x8*)&Vth[vro]; \
    bf16x8 vl = *(const bf16x8*)&Vtl[vro]; \
    ac##j = MFMA_B16(ph0, vh, ac##j); \
    ac##j = MFMA_B16(pl0, vh, ac##j); \
    ac##j = MFMA_B16(ph0, vl, ac##j); \
    vh = *(const bf16x8*)&Vth[vro + 32]; \
    vl = *(const bf16x8*)&Vtl[vro + 32]; \
    ac##j = MFMA_B16(ph1, vh, ac##j); \
    ac##j = MFMA_B16(pl1, vh, ac##j); \
    ac##j = MFMA_B16(ph1, vl, ac##j); \
}

// transposed V staging from a pre-split uint2 (4 u16 along d), token column toks
#define WRVT(dst, v2, m) { \
    dst[(sj * 4 + 16 * (m) + 0) * 72 + toks] = (u16)((v2).x); \
    dst[(sj * 4 + 16 * (m) + 1) * 72 + toks] = (u16)((v2).x >> 16); \
    dst[(sj * 4 + 16 * (m) + 2) * 72 + toks] = (u16)((v2).y); \
    dst[(sj * 4 + 16 * (m) + 3) * 72 + toks] = (u16)((v2).y >> 16); }

__global__ __launch_bounds__(256, 2)
void yat_flash_mfma(const u16* __restrict__ qh_g, const u16* __restrict__ ql_g,
                    const float* __restrict__ qn, const float* __restrict__ kn,
                    u16* __restrict__ outh, u16* __restrict__ outl,
                    float* __restrict__ an_g) {
    __shared__ __align__(16) u16 KPh[64 * 72], KPl[64 * 72];  // Q prologue; K; P after St
    __shared__ __align__(16) u16 Vth[64 * 72], Vtl[64 * 72];  // V^T [d][tok^swz]
    __shared__ float kns[64];

    const int tid = threadIdx.x;
    const int L = blockIdx.x;         // 0..767
    const int u = L / 48;
    const int qt = (u & 1) ? (u >> 1) : (15 - (u >> 1));
    const int bh = L % 48;
    const int h = bh % 12, b = bh / 12;
    const int wave = tid >> 6;
    const int lane = tid & 63;
    const int lm = lane & 15;
    const int kq = lane >> 4;
    const int kq4 = kq << 2;
    const int wband = wave << 4;
    const int sr = tid >> 2;          // staging token row 0..63
    const int sj = tid & 3;           // staging d-group
    const int toks = sr ^ (sj << 3);  // swizzled Vt column
    const int vkq8 = (kq ^ (lm >> 2)) << 3;
    const size_t base = (size_t)(b * 1024) * 2304 + h * 64;

    // ---- stage Q through KPh/KPl (only needed until frag reads) ----
    {
        const size_t qoff = base + (size_t)((qt << 6) + sr) * 2304 + sj * 16;
        *(uint4*)&KPh[sr * 72 + sj * 16]     = *(const uint4*)(qh_g + qoff);
        *(uint4*)&KPh[sr * 72 + sj * 16 + 8] = *(const uint4*)(qh_g + qoff + 8);
        *(uint4*)&KPl[sr * 72 + sj * 16]     = *(const uint4*)(ql_g + qoff);
        *(uint4*)&KPl[sr * 72 + sj * 16 + 8] = *(const uint4*)(ql_g + qoff + 8);
    }
    const float qnm = qn[bh * 1024 + (qt << 6) + wband + lm];

    // prefetch kt=0 K/V (pre-split u16) into registers
    const size_t r0 = base + (size_t)sr * 2304;
    uint4 kh0 = *(const uint4*)(qh_g + r0 + 768 + sj * 16);
    uint4 kh1 = *(const uint4*)(qh_g + r0 + 768 + sj * 16 + 8);
    uint4 kl0 = *(const uint4*)(ql_g + r0 + 768 + sj * 16);
    uint4 kl1 = *(const uint4*)(ql_g + r0 + 768 + sj * 16 + 8);
    uint2 vh0 = *(const uint2*)(qh_g + r0 + 1536 + sj * 4);
    uint2 vh1 = *(const uint2*)(qh_g + r0 + 1536 + sj * 4 + 16);
    uint2 vh2 = *(const uint2*)(qh_g + r0 + 1536 + sj * 4 + 32);
    uint2 vh3 = *(const uint2*)(qh_g + r0 + 1536 + sj * 4 + 48);
    uint2 vl0 = *(const uint2*)(ql_g + r0 + 1536 + sj * 4);
    uint2 vl1 = *(const uint2*)(ql_g + r0 + 1536 + sj * 4 + 16);
    uint2 vl2 = *(const uint2*)(ql_g + r0 + 1536 + sj * 4 + 32);
    uint2 vl3 = *(const uint2*)(ql_g + r0 + 1536 + sj * 4 + 48);
    float knS = (tid < 64) ? kn[bh * 1024 + tid] : 0.f;

    __syncthreads();  // Q staged

    // loop-invariant Q fragments (B-operand: Q^T via row-major Q)
    const int qrow = (wband + lm) * 72;
    const bf16x8 qh0 = *(const bf16x8*)&KPh[qrow + (kq << 3)];
    const bf16x8 qh1 = *(const bf16x8*)&KPh[qrow + 32 + (kq << 3)];
    const bf16x8 ql0 = *(const bf16x8*)&KPl[qrow + (kq << 3)];
    const bf16x8 ql1 = *(const bf16x8*)&KPl[qrow + 32 + (kq << 3)];

    f32x4 ac0 = {}, ac1 = {}, ac2 = {}, ac3 = {};
    float mrun = -3e38f, lrun = 0.f;
    const int pmrow = (wband + lm) * 72;

    for (int kt = 0; kt <= qt; ++kt) {
        __syncthreads();  // Q frag reads (iter0) / prior PV reads done
        *(uint4*)&KPh[sr * 72 + sj * 16]     = kh0;
        *(uint4*)&KPh[sr * 72 + sj * 16 + 8] = kh1;
        *(uint4*)&KPl[sr * 72 + sj * 16]     = kl0;
        *(uint4*)&KPl[sr * 72 + sj * 16 + 8] = kl1;
        WRVT(Vth, vh0, 0) WRVT(Vth, vh1, 1) WRVT(Vth, vh2, 2) WRVT(Vth, vh3, 3)
        WRVT(Vtl, vl0, 0) WRVT(Vtl, vl1, 1) WRVT(Vtl, vl2, 2) WRVT(Vtl, vl3, 3)
        if (tid < 64) kns[tid] = knS;
        __syncthreads();

        if (kt < qt) {  // prefetch kt+1 (block-uniform)
            const size_t r = base + (size_t)(((kt + 1) << 6) + sr) * 2304;
            kh0 = *(const uint4*)(qh_g + r + 768 + sj * 16);
            kh1 = *(const uint4*)(qh_g + r + 768 + sj * 16 + 8);
            kl0 = *(const uint4*)(ql_g + r + 768 + sj * 16);
            kl1 = *(const uint4*)(ql_g + r + 768 + sj * 16 + 8);
            vh0 = *(const uint2*)(qh_g + r + 1536 + sj * 4);
            vh1 = *(const uint2*)(qh_g + r + 1536 + sj * 4 + 16);
            vh2 = *(const uint2*)(qh_g + r + 1536 + sj * 4 + 32);
            vh3 = *(const uint2*)(qh_g + r + 1536 + sj * 4 + 48);
            vl0 = *(const uint2*)(ql_g + r + 1536 + sj * 4);
            vl1 = *(const uint2*)(ql_g + r + 1536 + sj * 4 + 16);
            vl2 = *(const uint2*)(ql_g + r + 1536 + sj * 4 + 32);
            vl3 = *(const uint2*)(ql_g + r + 1536 + sj * 4 + 48);
            if (tid < 64) knS = kn[bh * 1024 + ((kt + 1) << 6) + tid];
        }

        // ---- St = K.Q^T (each lane: one m = wband+lm, n = j*16+kq*4+r) ----
        f32x4 st0 = {}, st1 = {}, st2 = {}, st3 = {};
        __builtin_amdgcn_s_setprio(1);
        ST_TILE(0) ST_TILE(1) ST_TILE(2) ST_TILE(3)
        __builtin_amdgcn_s_setprio(0);
        __syncthreads();  // K frag reads done; P may overwrite KP

        // ---- yat score + mask + online softmax (per-lane row state) ----
        const bool diag = (kt == qt);
        float mm = -3e38f;
        YAT_TILE(0) YAT_TILE(1) YAT_TILE(2) YAT_TILE(3)
        mm = fmaxf(mm, __shfl_xor(mm, 16));
        mm = fmaxf(mm, __shfl_xor(mm, 32));
        const float mnew = fmaxf(mrun, mm);
        // T13 defer-max: wave-uniform skip of the O-rescale when no row's
        // max grew (al==1 exactly). Shfls inside are safe (uniform branch).
        if (!__all(mm <= mrun)) {
            const float al = __expf(mrun - mnew);
            const float a0 = __shfl(al, kq4 + 0, 16);
            const float a1 = __shfl(al, kq4 + 1, 16);
            const float a2 = __shfl(al, kq4 + 2, 16);
            const float a3 = __shfl(al, kq4 + 3, 16);
            ac0[0] *= a0; ac0[1] *= a1; ac0[2] *= a2; ac0[3] *= a3;
            ac1[0] *= a0; ac1[1] *= a1; ac1[2] *= a2; ac1[3] *= a3;
            ac2[0] *= a0; ac2[1] *= a1; ac2[2] *= a2; ac2[3] *= a3;
            ac3[0] *= a0; ac3[1] *= a1; ac3[2] *= a2; ac3[3] *= a3;
            lrun *= al;
        }
        mrun = mnew;
        float rs = 0.f;
        PEXP_TILE(0) PEXP_TILE(1) PEXP_TILE(2) PEXP_TILE(3)
        rs += __shfl_xor(rs, 16);
        rs += __shfl_xor(rs, 32);
        lrun += rs;
        __syncthreads();  // P writes visible

        // ---- O += P.V ----
        const bf16x8 ph0 = *(const bf16x8*)&KPh[pmrow + (kq << 3)];
        const bf16x8 ph1 = *(const bf16x8*)&KPh[pmrow + 32 + (kq << 3)];
        const bf16x8 pl0 = *(const bf16x8*)&KPl[pmrow + (kq << 3)];
        const bf16x8 pl1 = *(const bf16x8*)&KPl[pmrow + 32 + (kq << 3)];
        __builtin_amdgcn_s_setprio(1);
        PV_TILE(0) PV_TILE(1) PV_TILE(2) PV_TILE(3)
        __builtin_amdgcn_s_setprio(0);
    }

    const float i0 = 1.f / __shfl(lrun, kq4 + 0, 16);
    const float i1 = 1.f / __shfl(lrun, kq4 + 1, 16);
    const float i2 = 1.f / __shfl(lrun, kq4 + 2, 16);
    const float i3 = 1.f / __shfl(lrun, kq4 + 3, 16);
    const size_t obase = (size_t)(b * 1024 + (qt << 6) + wband + kq4) * 768 + h * 64 + lm;
    u16* oph = outh + obase;
    u16* opl = outl + obase;
    float rsum0 = 0.f, rsum1 = 0.f, rsum2 = 0.f, rsum3 = 0.f;
    #define STORE_E(j, r, iv) { \
        float ov = ac##j[r] * iv; \
        rsum##r += ov * ov; \
        u16 hh = bf16_rne(ov); \
        oph[(size_t)(r) * 768 + (j)*16] = hh; \
        opl[(size_t)(r) * 768 + (j)*16] = bf16_rne(ov - bf16_f(hh)); }
    #define STORE_T(j) { STORE_E(j,0,i0) STORE_E(j,1,i1) STORE_E(j,2,i2) STORE_E(j,3,i3) }
    STORE_T(0) STORE_T(1) STORE_T(2) STORE_T(3)
    #undef STORE_T
    #undef STORE_E
    // fused attn_out row-norm: reduce this wave's 64 head-cols per row, one
    // atomicAdd per (wave,row). 12 heads accumulate per row across blocks.
    const int arow = b * 1024 + (qt << 6) + wband + kq4;
    #define REDROW(r) { \
        float s = rsum##r; \
        s += __shfl_xor(s, 1, 16); \
        s += __shfl_xor(s, 2, 16); \
        s += __shfl_xor(s, 4, 16); \
        s += __shfl_xor(s, 8, 16); \
        if (lm == 0) atomicAdd(&an_g[arow + (r)], s); }
    REDROW(0) REDROW(1) REDROW(2) REDROW(3)
    #undef REDROW
}

extern "C" void kernel_launch(void* const* d_in, const int* in_sizes, int n_in,
                              void* d_out, int out_size, void* d_ws, size_t ws_size,
                              hipStream_t stream) {
    const float* x          = (const float*)d_in[0];
    // d_in[1] = mask (causal, known structure — unused)
    const float* W_attn     = (const float*)d_in[2];
    const float* b_attn     = (const float*)d_in[3];
    const float* alpha_attn = (const float*)d_in[4];
    const float* W_proj     = (const float*)d_in[5];
    const float* b_proj     = (const float*)d_in[6];
    const float* alpha_proj = (const float*)d_in[7];

    float* ws       = (float*)d_ws;
    u16*   qkvh     = (u16*)ws;              // [0, 4718592) f32-slots
    u16*   qkvl     = (u16*)(ws + 4718592);  // [4718592, 9437184)
    float* xn       = ws + 12582912;         // 4096
    float* an       = ws + 12587008;         // 4096 (zeroed by colnorm_reduce2; flash atomics)
    float* wn_attn  = ws + 12591104;         // 2304
    float* wn_proj  = ws + 12593408;         // 768
    float* qn       = ws + 12594176;         // 49152 (written by gemm1 epilogue)
    float* kn       = ws + 12643328;         // 49152

    // [9437184, 12582912) region timeline (serial stream):
    //   colnorm partials -> xh/xl (gemm1 inputs) -> aoh/aol (flash output)
    float* cn_part_a = ws + 9437184;              // 16*2304
    float* cn_part_p = ws + 9437184 + 36864;      // 16*768
    u16* xh  = (u16*)(ws + 9437184);
    u16* xl  = (u16*)(ws + 11010048);
    u16* aoh = (u16*)(ws + 9437184);              // flash h/l output (xh/xl dead)
    u16* aol = (u16*)(ws + 11010048);
    u16* wth = (u16*)d_out;
    u16* wtl = (u16*)d_out + 1769472;
    u16* wph = (u16*)(ws + 3145728);              // inside qkvh region (dead post-flash)
    u16* wpl = (u16*)(ws + 3440640);

    colnorm_part2<<<dim3(48, 16), 256, 0, stream>>>(W_attn, W_proj, cn_part_a, cn_part_p);
    colnorm_reduce2<<<28, 256, 0, stream>>>(cn_part_a, cn_part_p, wn_attn, wn_proj, an);
    split_rownorm<<<1024, 256, 0, stream>>>(x, xh, xl, xn);
    split_wt_kernel<<<dim3(36, 12), 256, 0, stream>>>(W_attn, wth, wtl, 768, 2304);
    yat_gemm_mfma<1, 2><<<dim3(18, 64), 256, 0, stream>>>(
        xh, xl, wth, wtl, b_attn, xn, wn_attn, alpha_attn, 2304.f,
        nullptr, qkvh, qkvl, qn, kn, 2304, 768);
    yat_flash_mfma<<<768, 256, 0, stream>>>(qkvh, qkvl, qn, kn, aoh, aol, an);
    split_wt_kernel<<<dim3(12, 12), 256, 0, stream>>>(W_proj, wph, wpl, 768, 768);
    yat_gemm_mfma<0, 1><<<dim3(12, 64), 256, 0, stream>>>(
        aoh, aol, wph, wpl, b_proj, an, wn_proj, alpha_proj, 768.f,
        (float*)d_out, nullptr, nullptr, nullptr, nullptr, 768, 768);
}